// Round 22
// baseline (167.359 us; speedup 1.0000x reference)
//
#include <hip/hip_runtime.h>
#include <stdint.h>

// Fused MLP decode, MFMA f16. ROUND 22: THE 4-WAVE OCCUPANCY EXPERIMENT.
// Discovery (R21 post-mortem): per m69, VGPR allocation quantizes at
// {64,128,256}; waves/SIMD = 512/quantum. Every kernel since R11 sat in
// (128,256] unified (e.g. R19: 72 arch + 64 AGPR weights = 136 -> alloc
// 256 -> EXACTLY 2 waves/SIMD) -- which is why occupancy resisted regs
// (R8), grid (R3/R4), and LDS (R11) all session. Target: unified <= 128
// = 64 arch + 64 AGPR -> 4 waves/SIMD -> 2x latency hiding.
// Cuts from R19 (lean single-tile base, 91.5us @ 2 waves):
//   - b1 -> packed f16 biash (8 regs, R15-proven; bias via v_fma_mix)
//   - dot-MFMA C = z; boutBL added in scalar epilogue (-4 regs)
//   - lb(256,4), grid 1024 = 4 blocks/CU
// PRE-COMMITTED READS: VGPR_Count should be 64 (cap signature). Success:
// Occupancy 25 -> ~45-50, dur -> 65-80us, WRITE stays 7812.5 -> KEEP.
// Failure: WRITE/FETCH jump (spill) or occupancy ~25 -> revert to R21.
// Kept (validated): zero-LDS loop + modulo-2 interleave (R12), weights
// AGPR-resident (R4/R8), hmap-permuted W1 (R11), staged-Wout dot-MFMA
// (R16), usilu1 (R15), split Chebyshev (R17), f16 emb table in d_ws (R19),
// tix/rho 2-ahead + emb 1-ahead prefetch (R13 lesson).
// Loop: zero DS ops, zero barriers.

typedef _Float16 half8  __attribute__((ext_vector_type(8)));
typedef _Float16 half4v __attribute__((ext_vector_type(4)));
typedef _Float16 half2v __attribute__((ext_vector_type(2)));
typedef float f32x4 __attribute__((ext_vector_type(4)));

#define LOG2E 1.44269504088896340736f
#define NLN2  -0.6931471805599453f         // -ln2 = 1/(-log2e)
#define CSCL  -1.44269504088896340736f     // c = -log2e
#define BASE_LOGIT -0.84729786038720367f   // log(0.3/0.7)
#define CSANMAX 28700.0f
#define IC_VAL 8610.0f                     // 0.3 * 28700

__device__ __forceinline__ float fast_exp2(float x) { return __builtin_amdgcn_exp2f(x); }
__device__ __forceinline__ float fast_rcp(float x)  { return __builtin_amdgcn_rcpf(x); }
// direct u-domain silu: input u (= c*x), output p = u*sigma = c*silu(x).
__device__ __forceinline__ float usilu1(float u) {
  return u * fast_rcp(1.0f + fast_exp2(u));
}
__device__ __forceinline__ half2v pkh(float a, float b) {
  return __builtin_bit_cast(half2v, __builtin_amdgcn_cvt_pkrtz(a, b));
}

union H8 { half8 v8; half2v v2[4]; half4v v4[2]; };
union H4 { half4v v4; half2v v2[2]; };

// ---- pre-kernel: emb (511x32 f32) -> f16 once, cvt_pkrtz rounding ----
__global__ __launch_bounds__(256) void emb_cvt(
    const float* __restrict__ emb, _Float16* __restrict__ embh, int nelem2)
{
  const int i = blockIdx.x * 256 + threadIdx.x;   // one f16 PAIR per thread
  if (i < nelem2) {
    const float a = emb[i * 2];
    const float b = emb[i * 2 + 1];
    *(half2v*)&embh[i * 2] = pkh(a, b);           // same rounding as R18
  }
}

__global__ __launch_bounds__(256, 4) void mlp_kernel(
    const int* __restrict__ tix, const float* __restrict__ rho,
    const _Float16* __restrict__ embh, const float* __restrict__ W0,
    const float* __restrict__ b0, const float* __restrict__ W1,
    const float* __restrict__ b1, const float* __restrict__ Wout,
    const float* __restrict__ bout, float* __restrict__ out, int ntiles)
{
  // Weight staging ONLY (init, 16384 B). 4 blocks/CU -> 64 KB, fits.
  __shared__ __align__(16) _Float16 stage[2][2][4][64][8];

  const int tid  = threadIdx.x;
  const int wid  = tid >> 6;
  const int lane = tid & 63;
  const int m    = lane & 15;
  const int q    = lane >> 4;

  // ---- init: wave 0 builds the swizzled weight fragments ----
  // W0 (A-op, => W0^T): k=s*32+q*8+j, n=t*16+m; feature rows PERMUTED
  // (k-window 32..63 = [cos1..8|sin1..8|rho,b0(1.0),0pad]); pre-scaled by c.
  // W1 (A-op, => W1^T): rows hmap-permuted so L1's B-operand is L0's
  // register output directly: hmap(k) = (s*2+(j>>2))*16 + q*4 + (j&3).
  if (wid == 0) {
#pragma unroll
    for (int t = 0; t < 4; ++t) {
#pragma unroll
      for (int s = 0; s < 2; ++s) {
        half8 f0, f1;
#pragma unroll
        for (int j = 0; j < 8; ++j) {
          const int k = s * 32 + q * 8 + j;
          const int n = t * 16 + m;
          float v0;
          if (k < 32) {
            v0 = W0[k * 64 + n];
          } else {
            const int kn = k - 32;
            v0 = (kn < 16) ? W0[(33 + kn) * 64 + n]
               : (kn == 16) ? W0[32 * 64 + n]
               : (kn == 17) ? b0[n] : 0.0f;
          }
          f0[j] = (_Float16)(CSCL * v0);
          const int hm = (s * 2 + (j >> 2)) * 16 + q * 4 + (j & 3);
          f1[j] = (_Float16)W1[hm * 64 + n];   // W1 UNSCALED, hmap-permuted
        }
        *(half8*)&stage[0][s][t][lane][0] = f0;
        *(half8*)&stage[1][s][t][lane][0] = f1;
      }
    }
  }

  // ---- persistent epilogue constants (register-minimal) ----
  // b1 packed f16 (8 regs), consumed via v_fma_mix: h = t*16 + q*4 + r.
  half2v biash[8];
#pragma unroll
  for (int t = 0; t < 4; ++t) {
    const f32x4 bv = *(const f32x4*)(b1 + t * 16 + q * 4);
    biash[t * 2]     = pkh(CSCL * bv[0], CSCL * bv[1]);
    biash[t * 2 + 1] = pkh(CSCL * bv[2], CSCL * bv[3]);
  }
  // Wout as dot-MFMA A-fragments (rows identical; -ln2-scaled):
  // A[row=*][k=q*8+j] = NLN2 * Wout[h'], h' = (j>>2)*16+q*4+(j&3) (+32 B-half).
  H8 wdA, wdB;
#pragma unroll
  for (int a = 0; a < 4; ++a) {
    const int j0 = 2 * a, j1 = 2 * a + 1;
    const int h0 = ((j0 >> 2) * 16) + q * 4 + (j0 & 3);
    const int h1 = ((j1 >> 2) * 16) + q * 4 + (j1 & 3);
    wdA.v2[a] = pkh(NLN2 * Wout[h0],      NLN2 * Wout[h1]);
    wdB.v2[a] = pkh(NLN2 * Wout[32 + h0], NLN2 * Wout[32 + h1]);
  }
  const float boutBL = bout[0] + BASE_LOGIT;   // SGPR (uniform scalar)

  __syncthreads();   // staged weights visible

  // ---- hoist ALL weight fragments to registers (loop-invariant, AGPR) ----
  half8 w0A[4], w0B[4], w1A[4], w1B[4];
#pragma unroll
  for (int t = 0; t < 4; ++t) {
    w0A[t] = *(const half8*)&stage[0][0][t][lane][0];
    w0B[t] = *(const half8*)&stage[0][1][t][lane][0];
    w1A[t] = *(const half8*)&stage[1][0][t][lane][0];
    w1B[t] = *(const half8*)&stage[1][1][t][lane][0];
  }

  const f32x4 z = {0.0f, 0.0f, 0.0f, 0.0f};
  const int S = gridDim.x * 4;

  int tg = blockIdx.x * 4 + wid;
  if (tg >= ntiles) return;          // after the barrier: safe
  const int lim = ntiles - 1;

  // ---- phase1: feat -> L0 -> silu -> packed Y (registers only) ----
  auto phase1 = [&](float rhp, half8 X0v, H8& Y0o, H8& Y1o) {
    const float rev = 0.5f * rhp;  // v_sin/v_cos take revolutions
    const float c1  = __builtin_amdgcn_cosf(rev);
    const float s1f = __builtin_amdgcn_sinf(rev);
    const float tc  = 2.0f * c1;
    const float x1v = (q == 0) ? c1 : ((q == 1) ? s1f : 0.0f);
    const float x0v = (q == 0) ? 1.0f : 0.0f;
    // even/odd split: x_{k+2} = uu*x_k - x_{k-2}, uu = 2cos(2a) = tc^2-2.
    const float x2v = tc * x1v - x0v;
    const float x3v = tc * x2v - x1v;
    const float uu  = tc * tc - 2.0f;
    const float x4v = uu * x2v - x0v;
    const float x5v = uu * x3v - x1v;
    const float x6v = uu * x4v - x2v;
    const float x7v = uu * x5v - x3v;
    const float x8v = uu * x6v - x4v;
    H8 X1;
    X1.v2[0] = (q == 2) ? pkh(rhp, 1.0f) : pkh(x1v, x2v);  // q==2: (rho, b0-slot)
    X1.v2[1] = pkh(x3v, x4v);
    X1.v2[2] = pkh(x5v, x6v);
    X1.v2[3] = pkh(x7v, x8v);

    f32x4 acc[4];
#pragma unroll
    for (int t = 0; t < 4; ++t) {
      f32x4 a = __builtin_amdgcn_mfma_f32_16x16x32_f16(w0A[t], X0v, z, 0, 0, 0);
      a = __builtin_amdgcn_mfma_f32_16x16x32_f16(w0B[t], X1.v8, a, 0, 0, 0);
      acc[t] = a;
    }
    H4 hh[4];
#pragma unroll
    for (int t = 0; t < 4; ++t) {
      hh[t].v2[0] = pkh(usilu1(acc[t][0]), usilu1(acc[t][1]));
      hh[t].v2[1] = pkh(usilu1(acc[t][2]), usilu1(acc[t][3]));
    }
    Y0o.v4[0] = hh[0].v4; Y0o.v4[1] = hh[1].v4;   // hmap makes this exact
    Y1o.v4[0] = hh[2].v4; Y1o.v4[1] = hh[3].v4;
  };

  // ---- phase2: L1(carried Y) -> bias(mix)+silu -> dot-MFMA -> store ----
  auto phase2 = [&](const H8& Y0p, const H8& Y1p, int icP, int tgP) {
    f32x4 acc[4];
#pragma unroll
    for (int t = 0; t < 4; ++t) {
      f32x4 a = __builtin_amdgcn_mfma_f32_16x16x32_f16(w1A[t], Y0p.v8, z, 0, 0, 0);
      a = __builtin_amdgcn_mfma_f32_16x16x32_f16(w1B[t], Y1p.v8, a, 0, 0, 0);
      acc[t] = a;
    }
    H4 hh2[4];
#pragma unroll
    for (int t = 0; t < 4; ++t) {
      const float u0 = (float)biash[t * 2][0]     + acc[t][0];  // v_fma_mix
      const float u1 = (float)biash[t * 2][1]     + acc[t][1];
      const float u2 = (float)biash[t * 2 + 1][0] + acc[t][2];
      const float u3 = (float)biash[t * 2 + 1][1] + acc[t][3];
      hh2[t].v2[0] = pkh(usilu1(u0), usilu1(u1));
      hh2[t].v2[1] = pkh(usilu1(u2), usilu1(u3));
    }
    H8 B0, B1;
    B0.v4[0] = hh2[0].v4; B0.v4[1] = hh2[1].v4;   // B[k][col=m], h'(k) staged
    B1.v4[0] = hh2[2].v4; B1.v4[1] = hh2[3].v4;
    f32x4 d2 = __builtin_amdgcn_mfma_f32_16x16x32_f16(wdA.v8, B0.v8, z, 0, 0, 0);
    d2 = __builtin_amdgcn_mfma_f32_16x16x32_f16(wdB.v8, B1.v8, d2, 0, 0, 0);
    // all A rows equal -> every lane's d2[0] = dot(point m); +boutBL (SGPR)
    const float theta = fast_rcp(1.0f + fast_exp2(-LOG2E * (d2[0] + boutBL)));
    const float val = (icP == 0) ? IC_VAL : theta * CSANMAX;
    if (q == 0) out[tgP * 16 + m] = val;
  };

  // ---- prologue: run phase1 on tile tg; prep inputs for tile tg+S ----
  int   tC = tix[tg * 16 + m];
  float rC = rho[tg * 16 + m];
  const int tg1 = min(tg + S, lim);
  int   tN = tix[tg1 * 16 + m];
  float rN = rho[tg1 * 16 + m];
  H8 X0C;
  X0C.v8 = *(const half8*)(embh + (size_t)min(max(tC - 1, 0), 510) * 32 + q * 8);
  H8 Y0p, Y1p;
  phase1(rC, X0C.v8, Y0p, Y1p);
  int icP = tC, tgP = tg;
  X0C.v8 = *(const half8*)(embh + (size_t)min(max(tN - 1, 0), 510) * 32 + q * 8);
  tC = tN; rC = rN;
  {
    const int tg2 = min(tg + 2 * S, lim);
    tN = tix[tg2 * 16 + m];
    rN = rho[tg2 * 16 + m];
  }
  tg += S;

  // ---- steady state: phase2(tile k-1, carried Y) ; phase1(tile k) ----
  while (tg < ntiles) {
    // prefetch: tix/rho 2 tiles ahead; emb 1 tile ahead (tN is >=1 iter old)
    const int tg2 = min(tg + 2 * S, lim);
    const int   tQ = tix[tg2 * 16 + m];
    const float rQ = rho[tg2 * 16 + m];
    const half8 X0N = *(const half8*)(embh + (size_t)min(max(tN - 1, 0), 510) * 32 + q * 8);

    phase2(Y0p, Y1p, icP, tgP);        // finish previous tile (reg-only deps)
    phase1(rC, X0C.v8, Y0p, Y1p);      // start current tile (independent)

    icP = tC; tgP = tg;
    X0C.v8 = X0N;                      // fragment carried directly, no repack
    tC = tN; rC = rN;
    tN = tQ; rN = rQ;
    tg += S;
  }

  // ---- epilogue: drain the last tile ----
  phase2(Y0p, Y1p, icP, tgP);
}

extern "C" void kernel_launch(void* const* d_in, const int* in_sizes, int n_in,
                              void* d_out, int out_size, void* d_ws, size_t ws_size,
                              hipStream_t stream) {
  const int*   tix  = (const int*)d_in[0];
  const float* rho  = (const float*)d_in[1];
  const float* emb  = (const float*)d_in[2];
  const float* W0   = (const float*)d_in[3];
  const float* b0   = (const float*)d_in[4];
  const float* W1   = (const float*)d_in[5];
  const float* b1   = (const float*)d_in[6];
  const float* Wout = (const float*)d_in[7];
  const float* bout = (const float*)d_in[8];
  float* outp = (float*)d_out;

  const int n      = in_sizes[0];    // 2,000,000 (divisible by 16)
  const int ntiles = n / 16;         // 125,000 tiles of 16 points

  // ---- one-time emb f32->f16 into workspace (32704 B) ----
  _Float16* embh = (_Float16*)d_ws;
  const int nelem2 = (511 * 32) / 2;               // f16 pairs
  emb_cvt<<<dim3((nelem2 + 255) / 256), dim3(256), 0, stream>>>(emb, embh, nelem2);

  // 4-wave blocks, 16384 B LDS. Grid 1024 = 4 blocks/CU target (the 4-wave
  // experiment); each wave runs ~30.5 tiles.
  int grid = 1024;
  const int maxg = (ntiles + 3) / 4;
  if (grid > maxg) grid = maxg;
  mlp_kernel<<<dim3(grid), dim3(256), 0, stream>>>(
      tix, rho, embh, W0, b0, W1, b1, Wout, bout, outp, ntiles);
}

// Round 23
// 155.193 us; speedup vs baseline: 1.0784x; 1.0784x over previous
//
#include <hip/hip_runtime.h>
#include <stdint.h>

// Fused MLP decode, MFMA f16. ROUND 23 (FINAL = R21 revert).
// R22 verdict: lb(256,4) cap=128 unified -> VGPR 64 + occupancy 33% (m69
// quantization model CONFIRMED: occupancy was register-quantum-pinned all
// session) but ~22 regs/loop spilled (WRITE 7.8->17.0MB) -> 102us >> 85.7.
// Demand ~150 unified (64 AGPR weights + ~86 arch) cannot fit 128 without
// dismantling validated structure worth more than the occupancy gain.
// Pre-committed revert: R21 quad pipeline is the session best
// (85.7-87.7us kernel; 1.9x over session start).
// Final structure: zero-LDS loop, 4-tile modulo-2 interleave, weights
// AGPR-resident (R4/R8), hmap-permuted W1 => register-direct L1 (R11),
// b1 as true MFMA C-operand (R18), staged-Wout dot-MFMA epilogue (R16),
// usilu1 u-domain silu (R15), split Chebyshev (R17), f16 emb table in
// d_ws (R19), grid 512 = 2 blocks/CU (R17), tix/rho 2-ahead + emb
// 1-ahead prefetch (R13 lesson: no same-iteration vmem deps), lb(256,2).
// Loop: zero DS ops, zero barriers. n % 64 == 0 (2,000,000 = 64*31,250).

typedef _Float16 half8  __attribute__((ext_vector_type(8)));
typedef _Float16 half4v __attribute__((ext_vector_type(4)));
typedef _Float16 half2v __attribute__((ext_vector_type(2)));
typedef float f32x4 __attribute__((ext_vector_type(4)));

#define LOG2E 1.44269504088896340736f
#define NLN2  -0.6931471805599453f         // -ln2 = 1/(-log2e)
#define CSCL  -1.44269504088896340736f     // c = -log2e
#define BASE_LOGIT -0.84729786038720367f   // log(0.3/0.7)
#define CSANMAX 28700.0f
#define IC_VAL 8610.0f                     // 0.3 * 28700

__device__ __forceinline__ float fast_exp2(float x) { return __builtin_amdgcn_exp2f(x); }
__device__ __forceinline__ float fast_rcp(float x)  { return __builtin_amdgcn_rcpf(x); }
// direct u-domain silu: input u (= c*x), output p = u*sigma = c*silu(x).
__device__ __forceinline__ float usilu1(float u) {
  return u * fast_rcp(1.0f + fast_exp2(u));
}
__device__ __forceinline__ half2v pkh(float a, float b) {
  return __builtin_bit_cast(half2v, __builtin_amdgcn_cvt_pkrtz(a, b));
}

union H8 { half8 v8; half2v v2[4]; half4v v4[2]; };
union H4 { half4v v4; half2v v2[2]; };

// ---- pre-kernel: emb (511x32 f32) -> f16 once, cvt_pkrtz rounding ----
__global__ __launch_bounds__(256) void emb_cvt(
    const float* __restrict__ emb, _Float16* __restrict__ embh, int nelem2)
{
  const int i = blockIdx.x * 256 + threadIdx.x;   // one f16 PAIR per thread
  if (i < nelem2) {
    const float a = emb[i * 2];
    const float b = emb[i * 2 + 1];
    *(half2v*)&embh[i * 2] = pkh(a, b);           // same rounding as R18
  }
}

__global__ __launch_bounds__(256, 2) void mlp_kernel(
    const int* __restrict__ tix, const float* __restrict__ rho,
    const _Float16* __restrict__ embh, const float* __restrict__ W0,
    const float* __restrict__ b0, const float* __restrict__ W1,
    const float* __restrict__ b1, const float* __restrict__ Wout,
    const float* __restrict__ bout, float* __restrict__ out, int nquads)
{
  // Weight staging ONLY (init, 16384 B). No H buffer.
  __shared__ __align__(16) _Float16 stage[2][2][4][64][8];

  const int tid  = threadIdx.x;
  const int wid  = tid >> 6;
  const int lane = tid & 63;
  const int m    = lane & 15;
  const int q    = lane >> 4;

  // ---- init: wave 0 builds the swizzled weight fragments ----
  // W0 (A-op, => W0^T): k=s*32+q*8+j, n=t*16+m; feature rows PERMUTED
  // (k-window 32..63 = [cos1..8|sin1..8|rho,b0(1.0),0pad]); pre-scaled by c.
  // W1 (A-op, => W1^T): rows hmap-permuted so L1's B-operand is L0's
  // register output directly: hmap(k) = (s*2+(j>>2))*16 + q*4 + (j&3).
  if (wid == 0) {
#pragma unroll
    for (int t = 0; t < 4; ++t) {
#pragma unroll
      for (int s = 0; s < 2; ++s) {
        half8 f0, f1;
#pragma unroll
        for (int j = 0; j < 8; ++j) {
          const int k = s * 32 + q * 8 + j;
          const int n = t * 16 + m;
          float v0;
          if (k < 32) {
            v0 = W0[k * 64 + n];
          } else {
            const int kn = k - 32;
            v0 = (kn < 16) ? W0[(33 + kn) * 64 + n]
               : (kn == 16) ? W0[32 * 64 + n]
               : (kn == 17) ? b0[n] : 0.0f;
          }
          f0[j] = (_Float16)(CSCL * v0);
          const int hm = (s * 2 + (j >> 2)) * 16 + q * 4 + (j & 3);
          f1[j] = (_Float16)W1[hm * 64 + n];   // W1 UNSCALED, hmap-permuted
        }
        *(half8*)&stage[0][s][t][lane][0] = f0;
        *(half8*)&stage[1][s][t][lane][0] = f1;
      }
    }
  }

  // ---- persistent epilogue constants ----
  // b1 as TRUE L1 C-operand (u-domain): lane (q,m) owns h = t*16 + q*4 + r.
  f32x4 bq1acc[4];
#pragma unroll
  for (int t = 0; t < 4; ++t) {
    const f32x4 bv = *(const f32x4*)(b1 + t * 16 + q * 4);
#pragma unroll
    for (int r = 0; r < 4; ++r) bq1acc[t][r] = CSCL * bv[r];
  }
  // Wout as dot-MFMA A-fragments (rows identical; -ln2-scaled):
  // A[row=*][k=q*8+j] = NLN2 * Wout[h'], h' = (j>>2)*16+q*4+(j&3) (+32 B-half).
  H8 wdA, wdB;
#pragma unroll
  for (int a = 0; a < 4; ++a) {
    const int j0 = 2 * a, j1 = 2 * a + 1;
    const int h0 = ((j0 >> 2) * 16) + q * 4 + (j0 & 3);
    const int h1 = ((j1 >> 2) * 16) + q * 4 + (j1 & 3);
    wdA.v2[a] = pkh(NLN2 * Wout[h0],      NLN2 * Wout[h1]);
    wdB.v2[a] = pkh(NLN2 * Wout[32 + h0], NLN2 * Wout[32 + h1]);
  }
  const float boutBL = bout[0] + BASE_LOGIT;
  const f32x4 cBL = {boutBL, boutBL, boutBL, boutBL};   // dot-MFMA C-operand

  __syncthreads();   // staged weights visible

  // ---- hoist ALL weight fragments to registers (loop-invariant) ----
  half8 w0A[4], w0B[4], w1A[4], w1B[4];
#pragma unroll
  for (int t = 0; t < 4; ++t) {
    w0A[t] = *(const half8*)&stage[0][0][t][lane][0];
    w0B[t] = *(const half8*)&stage[0][1][t][lane][0];
    w1A[t] = *(const half8*)&stage[1][0][t][lane][0];
    w1B[t] = *(const half8*)&stage[1][1][t][lane][0];
  }

  const f32x4 z = {0.0f, 0.0f, 0.0f, 0.0f};
  const int W = gridDim.x * 4;

  int p = blockIdx.x * 4 + wid;      // quad index: tiles 4p..4p+3
  if (p >= nquads) return;           // after the barrier: safe
  const int plim = nquads - 1;

  // ---- phase1: feat -> L0 -> silu -> packed Y (registers only) ----
  auto phase1 = [&](float rhp, half8 X0v, H8& Y0o, H8& Y1o) {
    const float rev = 0.5f * rhp;  // v_sin/v_cos take revolutions
    const float c1  = __builtin_amdgcn_cosf(rev);
    const float s1f = __builtin_amdgcn_sinf(rev);
    const float tc  = 2.0f * c1;
    const float x1v = (q == 0) ? c1 : ((q == 1) ? s1f : 0.0f);
    const float x0v = (q == 0) ? 1.0f : 0.0f;
    // even/odd split: x_{k+2} = uu*x_k - x_{k-2}, uu = 2cos(2a) = tc^2-2.
    const float x2v = tc * x1v - x0v;
    const float x3v = tc * x2v - x1v;
    const float uu  = tc * tc - 2.0f;
    const float x4v = uu * x2v - x0v;
    const float x5v = uu * x3v - x1v;
    const float x6v = uu * x4v - x2v;
    const float x7v = uu * x5v - x3v;
    const float x8v = uu * x6v - x4v;
    H8 X1;
    X1.v2[0] = (q == 2) ? pkh(rhp, 1.0f) : pkh(x1v, x2v);  // q==2: (rho, b0-slot)
    X1.v2[1] = pkh(x3v, x4v);
    X1.v2[2] = pkh(x5v, x6v);
    X1.v2[3] = pkh(x7v, x8v);

    f32x4 acc[4];
#pragma unroll
    for (int t = 0; t < 4; ++t) {
      f32x4 a = __builtin_amdgcn_mfma_f32_16x16x32_f16(w0A[t], X0v, z, 0, 0, 0);
      a = __builtin_amdgcn_mfma_f32_16x16x32_f16(w0B[t], X1.v8, a, 0, 0, 0);
      acc[t] = a;
    }
    H4 hh[4];
#pragma unroll
    for (int t = 0; t < 4; ++t) {
      hh[t].v2[0] = pkh(usilu1(acc[t][0]), usilu1(acc[t][1]));
      hh[t].v2[1] = pkh(usilu1(acc[t][2]), usilu1(acc[t][3]));
    }
    Y0o.v4[0] = hh[0].v4; Y0o.v4[1] = hh[1].v4;   // hmap makes this exact
    Y1o.v4[0] = hh[2].v4; Y1o.v4[1] = hh[3].v4;
  };

  // ---- phase2core: L1(carried Y, C=c*b1) -> silu -> dot-MFMA -> theta ----
  auto phase2core = [&](const H8& Y0p, const H8& Y1p) -> float {
    f32x4 acc[4];
#pragma unroll
    for (int t = 0; t < 4; ++t) {
      f32x4 a = __builtin_amdgcn_mfma_f32_16x16x32_f16(w1A[t], Y0p.v8, bq1acc[t], 0, 0, 0);
      a = __builtin_amdgcn_mfma_f32_16x16x32_f16(w1B[t], Y1p.v8, a, 0, 0, 0);
      acc[t] = a;   // u = W1^T p + c*b1 (bias folded into MFMA C)
    }
    H4 hh2[4];
#pragma unroll
    for (int t = 0; t < 4; ++t) {
      hh2[t].v2[0] = pkh(usilu1(acc[t][0]), usilu1(acc[t][1]));
      hh2[t].v2[1] = pkh(usilu1(acc[t][2]), usilu1(acc[t][3]));
    }
    H8 B0, B1;
    B0.v4[0] = hh2[0].v4; B0.v4[1] = hh2[1].v4;   // B[k][col=m], h'(k) staged
    B1.v4[0] = hh2[2].v4; B1.v4[1] = hh2[3].v4;
    f32x4 d2 = __builtin_amdgcn_mfma_f32_16x16x32_f16(wdA.v8, B0.v8, cBL, 0, 0, 0);
    d2 = __builtin_amdgcn_mfma_f32_16x16x32_f16(wdB.v8, B1.v8, d2, 0, 0, 0);
    // all A rows equal -> every lane's d2[0] = dot(point m) + boutBL
    return fast_rcp(1.0f + fast_exp2(-LOG2E * d2[0]));
  };

  // ---- pipeline state (explicit scalars: rule-#20 safe) ----
  int   tCa, tCb, tCc, tCd, tNa, tNb, tNc, tNd;
  int   icPa, icPb, icPc, icPd, pP;
  float rCa, rCb, rCc, rCd, rNa, rNb, rNc, rNd;
  H8 X0Ca, X0Cb, X0Cc, X0Cd;
  H8 Ya0, Ya1, Yb0, Yb1, Yc0, Yc1, Yd0, Yd1;

  // ---- prologue: fill pipe with quad p; prep quad p+W ----
  tCa = tix[p * 64 + m];      rCa = rho[p * 64 + m];
  tCb = tix[p * 64 + 16 + m]; rCb = rho[p * 64 + 16 + m];
  tCc = tix[p * 64 + 32 + m]; rCc = rho[p * 64 + 32 + m];
  tCd = tix[p * 64 + 48 + m]; rCd = rho[p * 64 + 48 + m];
  {
    const int p1 = min(p + W, plim);
    tNa = tix[p1 * 64 + m];      rNa = rho[p1 * 64 + m];
    tNb = tix[p1 * 64 + 16 + m]; rNb = rho[p1 * 64 + 16 + m];
    tNc = tix[p1 * 64 + 32 + m]; rNc = rho[p1 * 64 + 32 + m];
    tNd = tix[p1 * 64 + 48 + m]; rNd = rho[p1 * 64 + 48 + m];
  }
  X0Ca.v8 = *(const half8*)(embh + (size_t)min(max(tCa - 1, 0), 510) * 32 + q * 8);
  X0Cb.v8 = *(const half8*)(embh + (size_t)min(max(tCb - 1, 0), 510) * 32 + q * 8);
  X0Cc.v8 = *(const half8*)(embh + (size_t)min(max(tCc - 1, 0), 510) * 32 + q * 8);
  X0Cd.v8 = *(const half8*)(embh + (size_t)min(max(tCd - 1, 0), 510) * 32 + q * 8);
  phase1(rCa, X0Ca.v8, Ya0, Ya1);
  phase1(rCb, X0Cb.v8, Yb0, Yb1);
  phase1(rCc, X0Cc.v8, Yc0, Yc1);
  phase1(rCd, X0Cd.v8, Yd0, Yd1);
  icPa = tCa; icPb = tCb; icPc = tCc; icPd = tCd; pP = p;
  X0Ca.v8 = *(const half8*)(embh + (size_t)min(max(tNa - 1, 0), 510) * 32 + q * 8);
  X0Cb.v8 = *(const half8*)(embh + (size_t)min(max(tNb - 1, 0), 510) * 32 + q * 8);
  X0Cc.v8 = *(const half8*)(embh + (size_t)min(max(tNc - 1, 0), 510) * 32 + q * 8);
  X0Cd.v8 = *(const half8*)(embh + (size_t)min(max(tNd - 1, 0), 510) * 32 + q * 8);
  tCa = tNa; rCa = rNa; tCb = tNb; rCb = rNb;
  tCc = tNc; rCc = rNc; tCd = tNd; rCd = rNd;
  {
    const int p2 = min(p + 2 * W, plim);
    tNa = tix[p2 * 64 + m];      rNa = rho[p2 * 64 + m];
    tNb = tix[p2 * 64 + 16 + m]; rNb = rho[p2 * 64 + 16 + m];
    tNc = tix[p2 * 64 + 32 + m]; rNc = rho[p2 * 64 + 32 + m];
    tNd = tix[p2 * 64 + 48 + m]; rNd = rho[p2 * 64 + 48 + m];
  }
  p += W;

  // ---- steady state: 4x phase2(quad k-1) ; 4x phase1(quad k) ----
  while (p < nquads) {
    // prefetch: tix/rho 2 quads ahead; emb 1 quad ahead (tN >=1 iter old)
    const int pf = min(p + 2 * W, plim);
    const int   tQa = tix[pf * 64 + m],      tQb = tix[pf * 64 + 16 + m];
    const int   tQc = tix[pf * 64 + 32 + m], tQd = tix[pf * 64 + 48 + m];
    const float rQa = rho[pf * 64 + m],      rQb = rho[pf * 64 + 16 + m];
    const float rQc = rho[pf * 64 + 32 + m], rQd = rho[pf * 64 + 48 + m];
    const half8 X0Na = *(const half8*)(embh + (size_t)min(max(tNa - 1, 0), 510) * 32 + q * 8);
    const half8 X0Nb = *(const half8*)(embh + (size_t)min(max(tNb - 1, 0), 510) * 32 + q * 8);
    const half8 X0Nc = *(const half8*)(embh + (size_t)min(max(tNc - 1, 0), 510) * 32 + q * 8);
    const half8 X0Nd = *(const half8*)(embh + (size_t)min(max(tNd - 1, 0), 510) * 32 + q * 8);

    // finish quad k-1: {a,b} then 128B store (acc state dies), {c,d} + store
    {
      const float tha = phase2core(Ya0, Ya1);
      const float thb = phase2core(Yb0, Yb1);
      const float vala = (icPa == 0) ? IC_VAL : tha * CSANMAX;
      const float valb = (icPb == 0) ? IC_VAL : thb * CSANMAX;
      if (q < 2) out[pP * 64 + q * 16 + m] = (q & 1) ? valb : vala;
    }
    {
      const float thc = phase2core(Yc0, Yc1);
      const float thd = phase2core(Yd0, Yd1);
      const float valc = (icPc == 0) ? IC_VAL : thc * CSANMAX;
      const float vald = (icPd == 0) ? IC_VAL : thd * CSANMAX;
      if (q < 2) out[pP * 64 + 32 + q * 16 + m] = (q & 1) ? vald : valc;
    }
    // start quad k: four independent L0 chains
    phase1(rCa, X0Ca.v8, Ya0, Ya1);
    phase1(rCb, X0Cb.v8, Yb0, Yb1);
    phase1(rCc, X0Cc.v8, Yc0, Yc1);
    phase1(rCd, X0Cd.v8, Yd0, Yd1);

    icPa = tCa; icPb = tCb; icPc = tCc; icPd = tCd; pP = p;
    X0Ca.v8 = X0Na; X0Cb.v8 = X0Nb; X0Cc.v8 = X0Nc; X0Cd.v8 = X0Nd;
    tCa = tNa; rCa = rNa; tCb = tNb; rCb = rNb;
    tCc = tNc; rCc = rNc; tCd = tNd; rCd = rNd;
    tNa = tQa; rNa = rQa; tNb = tQb; rNb = rQb;
    tNc = tQc; rNc = rQc; tNd = tQd; rNd = rQd;
    p += W;
  }

  // ---- epilogue: drain the last quad ----
  {
    const float tha = phase2core(Ya0, Ya1);
    const float thb = phase2core(Yb0, Yb1);
    const float vala = (icPa == 0) ? IC_VAL : tha * CSANMAX;
    const float valb = (icPb == 0) ? IC_VAL : thb * CSANMAX;
    if (q < 2) out[pP * 64 + q * 16 + m] = (q & 1) ? valb : vala;
    const float thc = phase2core(Yc0, Yc1);
    const float thd = phase2core(Yd0, Yd1);
    const float valc = (icPc == 0) ? IC_VAL : thc * CSANMAX;
    const float vald = (icPd == 0) ? IC_VAL : thd * CSANMAX;
    if (q < 2) out[pP * 64 + 32 + q * 16 + m] = (q & 1) ? vald : valc;
  }
}

extern "C" void kernel_launch(void* const* d_in, const int* in_sizes, int n_in,
                              void* d_out, int out_size, void* d_ws, size_t ws_size,
                              hipStream_t stream) {
  const int*   tix  = (const int*)d_in[0];
  const float* rho  = (const float*)d_in[1];
  const float* emb  = (const float*)d_in[2];
  const float* W0   = (const float*)d_in[3];
  const float* b0   = (const float*)d_in[4];
  const float* W1   = (const float*)d_in[5];
  const float* b1   = (const float*)d_in[6];
  const float* Wout = (const float*)d_in[7];
  const float* bout = (const float*)d_in[8];
  float* outp = (float*)d_out;

  const int n      = in_sizes[0];    // 2,000,000 (divisible by 64)
  const int nquads = n / 64;         // 31,250 quads of 16-pt tiles

  // ---- one-time emb f32->f16 into workspace (32704 B) ----
  _Float16* embh = (_Float16*)d_ws;
  const int nelem2 = (511 * 32) / 2;               // f16 pairs
  emb_cvt<<<dim3((nelem2 + 255) / 256), dim3(256), 0, stream>>>(emb, embh, nelem2);

  // 4-wave blocks, 16384 B LDS. Grid 512 = 2 blocks/CU; each wave runs
  // ~15.3 quad-iterations (61 tiles).
  int grid = 512;
  const int maxg = (nquads + 3) / 4;
  if (grid > maxg) grid = maxg;
  mlp_kernel<<<dim3(grid), dim3(256), 0, stream>>>(
      tix, rho, embh, W0, b0, W1, b1, Wout, bout, outp, nquads);
}